// Round 7
// baseline (291.610 us; speedup 1.0000x reference)
//
#include <hip/hip_runtime.h>
#include <hip/hip_bf16.h>
#include <cstdint>

#define NB 2
#define NSEQ 2048
#define NDIM 512
#define NHEAD 8
#define DHEAD 32
#define NINNER 256
#define NQKV 768
#define LNEPS 1e-5f
#define QSCALE 0.17677669529663687f

typedef short short8 __attribute__((ext_vector_type(8)));
typedef float f32x4 __attribute__((ext_vector_type(4)));
typedef unsigned int u32x4 __attribute__((ext_vector_type(4)));
typedef unsigned int u32x2 __attribute__((ext_vector_type(2)));
typedef unsigned short u16;
typedef unsigned int u32;

__device__ __forceinline__ f32x4 mfma16(short8 a, short8 b, f32x4 c) {
    return __builtin_amdgcn_mfma_f32_16x16x32_bf16(a, b, c, 0, 0, 0);
}

__device__ __forceinline__ u16 f2bf(float a) {
    union { float f; u32 u; } x; x.f = a;
    u32 r = x.u + 0x7fffu + ((x.u >> 16) & 1u);
    return (u16)(r >> 16);
}
__device__ __forceinline__ float bf2f(u16 h) {
    union { float f; u32 u; } x; x.u = ((u32)h) << 16; return x.f;
}
__device__ __forceinline__ void split2(float a, u16& hi, u16& lo) {
    hi = f2bf(a);
    lo = f2bf(a - bf2f(hi));
}
__device__ __forceinline__ u32 pk2(float a, float b) {
    return (u32)f2bf(a) | ((u32)f2bf(b) << 16);
}

// ---------------- Kernel 1: LayerNorm + bf16 hi/lo split ----------------
__global__ __launch_bounds__(256) void ln_kernel(
    const float* __restrict__ x, const float* __restrict__ gamma,
    u32* __restrict__ xn_hi, u32* __restrict__ xn_lo)
{
    const int row = blockIdx.x;
    const int t = threadIdx.x;
    const float2 v = ((const float2*)(x + (size_t)row * NDIM))[t];
    float s1 = v.x + v.y;
    float s2 = v.x * v.x + v.y * v.y;
    #pragma unroll
    for (int off = 32; off >= 1; off >>= 1) {
        s1 += __shfl_down(s1, off);
        s2 += __shfl_down(s2, off);
    }
    __shared__ float a1[4], a2[4];
    if ((t & 63) == 0) { a1[t >> 6] = s1; a2[t >> 6] = s2; }
    __syncthreads();
    const float ts1 = a1[0] + a1[1] + a1[2] + a1[3];
    const float ts2 = a2[0] + a2[1] + a2[2] + a2[3];
    const float mu = ts1 * (1.0f / NDIM);
    const float var = ts2 * (1.0f / NDIM) - mu * mu;
    const float rs = rsqrtf(var + LNEPS);
    const float2 g = ((const float2*)gamma)[t];
    u16 h0, l0, h1, l1;
    split2((v.x - mu) * rs * g.x, h0, l0);
    split2((v.y - mu) * rs * g.y, h1, l1);
    xn_hi[(size_t)row * (NDIM / 2) + t] = (u32)h0 | ((u32)h1 << 16);
    xn_lo[(size_t)row * (NDIM / 2) + t] = (u32)l0 | ((u32)l1 << 16);
}

// ---------------- Weight transpose + split, both weights in one launch ----------------
__global__ __launch_bounds__(256) void wtrans_kernel(
    const float* __restrict__ wq, u16* __restrict__ wqT_hi, u16* __restrict__ wqT_lo,
    const float* __restrict__ wo, u16* __restrict__ woT_hi, u16* __restrict__ woT_lo)
{
    __shared__ __align__(16) u16 th[64][72], tl[64][72];
    const int t = threadIdx.x;
    const float* w; u16 *wT_hi, *wT_lo; int K, N, k0, n0;
    if (blockIdx.x < 96) {
        w = wq; wT_hi = wqT_hi; wT_lo = wqT_lo; K = NDIM; N = NQKV;
        k0 = (blockIdx.x & 7) * 64; n0 = (blockIdx.x >> 3) * 64;
    } else {
        const int b = blockIdx.x - 96;
        w = wo; wT_hi = woT_hi; wT_lo = woT_lo; K = NINNER; N = NDIM;
        k0 = (b & 3) * 64; n0 = (b >> 2) * 64;
    }
    {
        const int k = t >> 2, c = (t & 3) * 16;
        const float* src = w + (size_t)(k0 + k) * N + n0 + c;
        #pragma unroll
        for (int jj = 0; jj < 4; jj++) {
            const f32x4 w4 = *(const f32x4*)(src + jj * 4);
            #pragma unroll
            for (int e = 0; e < 4; e++) {
                u16 hh, ll;
                split2(w4[e], hh, ll);
                th[k][c + jj * 4 + e] = hh;
                tl[k][c + jj * 4 + e] = ll;
            }
        }
    }
    __syncthreads();
    {
        const int n = t >> 2, kc = (t & 3) * 16;
        u16 hb[16], lb[16];
        #pragma unroll
        for (int j = 0; j < 16; j++) { hb[j] = th[kc + j][n]; lb[j] = tl[kc + j][n]; }
        u16* dh = wT_hi + (size_t)(n0 + n) * K + k0 + kc;
        u16* dl = wT_lo + (size_t)(n0 + n) * K + k0 + kc;
        *(short8*)dh = *(short8*)hb;
        *(short8*)(dh + 8) = *(short8*)(hb + 8);
        *(short8*)dl = *(short8*)lb;
        *(short8*)(dl + 8) = *(short8*)(lb + 8);
    }
}

// ---------------- V transpose: v[bh][N][32] bf16 -> vt[bh][32][N] ----------------
__global__ __launch_bounds__(256) void vtrans_kernel(
    const u16* __restrict__ v, u16* __restrict__ vt)
{
    __shared__ __align__(16) u16 sh[64][40];
    const int t = threadIdx.x;
    const int n0 = blockIdx.x * 64;
    const int bh = blockIdx.y;
    {
        const int n = t >> 2, c = (t & 3) * 8;
        *(short8*)&sh[n][c] = *(const short8*)(v + ((size_t)bh * NSEQ + n0 + n) * DHEAD + c);
    }
    __syncthreads();
    {
        const int d = t >> 3, nc = (t & 7) * 8;
        u16 buf[8];
        #pragma unroll
        for (int j = 0; j < 8; j++) buf[j] = sh[nc + j][d];
        *(short8*)(vt + ((size_t)bh * DHEAD + d) * NSEQ + n0 + nc) = *(short8*)buf;
    }
}

// ---------------- Kernel 2: QKV GEMM (64x64 tile, 4 waves, 12 MFMA/wave-iter) ----------------
__global__ __launch_bounds__(256, 4) void qkv_kernel(
    const u16* __restrict__ xn_hi, const u16* __restrict__ xn_lo,
    const u16* __restrict__ wT_hi, const u16* __restrict__ wT_lo,
    u16* __restrict__ q_hi, u16* __restrict__ q_lo,
    u16* __restrict__ k_hi,
    u16* __restrict__ v)
{
    __shared__ __align__(16) u16 Ah[64][40], Al[64][40], Bh[64][40], Bl[64][40];
    const int t = threadIdx.x;
    const int wave = t >> 6, lane = t & 63;
    const int lrow = lane & 15, lquad = lane >> 4;
    const int rowBase = blockIdx.x * 64;
    const int colBase = blockIdx.y * 64;
    const int wm = (wave & 1) * 32;
    const int wn = (wave >> 1) * 32;
    const int kf = lquad * 8;
    const f32x4 zero = {0.f, 0.f, 0.f, 0.f};
    f32x4 acc[2][2];
    acc[0][0] = zero; acc[0][1] = zero; acc[1][0] = zero; acc[1][1] = zero;

    const int sr = t >> 2, sc = (t & 3) * 8;

    for (int k0 = 0; k0 < NDIM; k0 += 32) {
        __syncthreads();
        *(short8*)&Ah[sr][sc] = *(const short8*)(xn_hi + (size_t)(rowBase + sr) * NDIM + k0 + sc);
        *(short8*)&Al[sr][sc] = *(const short8*)(xn_lo + (size_t)(rowBase + sr) * NDIM + k0 + sc);
        *(short8*)&Bh[sr][sc] = *(const short8*)(wT_hi + (size_t)(colBase + sr) * NDIM + k0 + sc);
        *(short8*)&Bl[sr][sc] = *(const short8*)(wT_lo + (size_t)(colBase + sr) * NDIM + k0 + sc);
        __syncthreads();
        const short8 a0h = *(const short8*)&Ah[wm + lrow][kf];
        const short8 a0l = *(const short8*)&Al[wm + lrow][kf];
        const short8 a1h = *(const short8*)&Ah[wm + 16 + lrow][kf];
        const short8 a1l = *(const short8*)&Al[wm + 16 + lrow][kf];
        const short8 b0h = *(const short8*)&Bh[wn + lrow][kf];
        const short8 b0l = *(const short8*)&Bl[wn + lrow][kf];
        const short8 b1h = *(const short8*)&Bh[wn + 16 + lrow][kf];
        const short8 b1l = *(const short8*)&Bl[wn + 16 + lrow][kf];
        acc[0][0] = mfma16(a0h, b0h, acc[0][0]); acc[0][0] = mfma16(a0h, b0l, acc[0][0]); acc[0][0] = mfma16(a0l, b0h, acc[0][0]);
        acc[0][1] = mfma16(a0h, b1h, acc[0][1]); acc[0][1] = mfma16(a0h, b1l, acc[0][1]); acc[0][1] = mfma16(a0l, b1h, acc[0][1]);
        acc[1][0] = mfma16(a1h, b0h, acc[1][0]); acc[1][0] = mfma16(a1h, b0l, acc[1][0]); acc[1][0] = mfma16(a1l, b0h, acc[1][0]);
        acc[1][1] = mfma16(a1h, b1h, acc[1][1]); acc[1][1] = mfma16(a1h, b1l, acc[1][1]); acc[1][1] = mfma16(a1l, b1h, acc[1][1]);
    }

    #pragma unroll
    for (int mi = 0; mi < 2; mi++) {
        #pragma unroll
        for (int ni = 0; ni < 2; ni++) {
            #pragma unroll
            for (int r = 0; r < 4; r++) {
                const int grow = rowBase + wm + mi * 16 + lquad * 4 + r;
                const int gcol = colBase + wn + ni * 16 + lrow;
                const float val = acc[mi][ni][r];
                const int bidx = grow >> 11;
                const int n = grow & (NSEQ - 1);
                const int sec = gcol >> 8;          // 0=q 1=k 2=v
                const int idx = gcol & 255;
                const int head = idx >> 5, d = idx & 31;
                const int bh = bidx * NHEAD + head;
                if (sec == 0) {
                    u16 hh, ll;
                    split2(val * QSCALE, hh, ll);
                    const size_t a = ((size_t)bh * NSEQ + n) * DHEAD + d;
                    q_hi[a] = hh; q_lo[a] = ll;
                } else if (sec == 1) {
                    k_hi[((size_t)bh * NSEQ + n) * DHEAD + d] = f2bf(val);
                } else {
                    v[((size_t)bh * NSEQ + n) * DHEAD + d] = f2bf(val);
                }
            }
        }
    }
}

// ---------------- Kernel 3: flash attention, 64 q/wave, deep pipeline ----------------
// Block = 512 threads = 8 waves = 2 q-tiles(64q) x 4 key-slices(512k); one (batch,head).
// Grid (16,16) = 256 blocks = exactly 1/CU. S^T = K.Q^T with kperm row permutation
// (C-layout quad holds keys lquad*8..+7 -> PV B-frag is in-lane packing).
// K is single-bf16 (k_lo term dropped); Q keeps hi+lo. Bias loads are NON-TEMPORAL
// (don't thrash L2; K/V stay L2-resident) and prefetched one iteration ahead, as is K.
__global__ __launch_bounds__(512, 2) void attn_kernel(
    const u16* __restrict__ q_hi, const u16* __restrict__ q_lo,
    const u16* __restrict__ k_hi,
    const u16* __restrict__ vt,
    const float* __restrict__ bias,
    u16* __restrict__ o_hi, u16* __restrict__ o_lo)
{
    __shared__ __align__(16) float cA[2][4][4][64][4];   // [qt][kslice][frag][lane][4]
    __shared__ __align__(16) float cB[2][4][4][64][4];
    __shared__ float cl[2][4][4][16];
    const int t = threadIdx.x;
    const int wave = t >> 6, lane = t & 63;
    const int lrow = lane & 15, lquad = lane >> 4;
    const int qt = wave >> 2, ks = wave & 3;
    const int bh = blockIdx.y;
    const int batch = bh >> 3, head = bh & 7;
    const int qbase = blockIdx.x * 128 + qt * 64;
    const size_t qkb = (size_t)bh * NSEQ * DHEAD;

    short8 qh[4], ql[4];
    #pragma unroll
    for (int f = 0; f < 4; f++) {
        const size_t qoff = (size_t)(qbase + f * 16 + lrow) * DHEAD + lquad * 8;
        qh[f] = *(const short8*)(q_hi + qkb + qoff);
        ql[f] = *(const short8*)(q_lo + qkb + qoff);
    }
    const f32x4 zero = {0.f, 0.f, 0.f, 0.f};
    f32x4 accA[4], accB[4];
    #pragma unroll
    for (int f = 0; f < 4; f++) { accA[f] = zero; accB[f] = zero; }
    float lp[4] = {0.f, 0.f, 0.f, 0.f};
    const int kperm = ((lrow >> 2) << 3) | (lrow & 3);
    const float* bp[4];
    #pragma unroll
    for (int f = 0; f < 4; f++)
        bp[f] = bias + (size_t)head * NSEQ * NSEQ + (size_t)(qbase + f * 16 + lrow) * NSEQ;
    const int kt0 = ks * 512;

    // prefetch iteration 0: K (L2) + bias (non-temporal, HBM stream)
    short8 kc0 = *(const short8*)(k_hi + qkb + (size_t)(kt0 + kperm) * DHEAD + lquad * 8);
    short8 kc1 = *(const short8*)(k_hi + qkb + (size_t)(kt0 + kperm + 4) * DHEAD + lquad * 8);
    f32x4 bc0[4], bc1[4];
    #pragma unroll
    for (int f = 0; f < 4; f++) {
        bc0[f] = __builtin_nontemporal_load((const f32x4*)(bp[f] + kt0 + lquad * 8));
        bc1[f] = __builtin_nontemporal_load((const f32x4*)(bp[f] + kt0 + lquad * 8 + 4));
    }

    for (int i = 0; i < 16; i++) {
        const int kt = kt0 + i * 32;
        const int ktn = kt0 + ((i + 1) & 15) * 32;
        // ---- prefetch next iteration's K + bias; current V ----
        const short8 kn0 = *(const short8*)(k_hi + qkb + (size_t)(ktn + kperm) * DHEAD + lquad * 8);
        const short8 kn1 = *(const short8*)(k_hi + qkb + (size_t)(ktn + kperm + 4) * DHEAD + lquad * 8);
        const short8 va0 = *(const short8*)(vt + qkb + (size_t)lrow * NSEQ + kt + lquad * 8);
        const short8 va1 = *(const short8*)(vt + qkb + (size_t)(16 + lrow) * NSEQ + kt + lquad * 8);
        f32x4 bn0[4], bn1[4];
        #pragma unroll
        for (int f = 0; f < 4; f++) {
            bn0[f] = __builtin_nontemporal_load((const f32x4*)(bp[f] + ktn + lquad * 8));
            bn1[f] = __builtin_nontemporal_load((const f32x4*)(bp[f] + ktn + lquad * 8 + 4));
        }
        // ---- compute on current registers ----
        #pragma unroll
        for (int f = 0; f < 4; f++) {
            f32x4 c0 = zero, c1 = zero;
            c0 = mfma16(kc0, qh[f], c0); c0 = mfma16(kc0, ql[f], c0);
            c1 = mfma16(kc1, qh[f], c1); c1 = mfma16(kc1, ql[f], c1);
            f32x4 p0, p1;
            #pragma unroll
            for (int r = 0; r < 4; r++) {
                p0[r] = __expf(c0[r] + bc0[f][r]);
                p1[r] = __expf(c1[r] + bc1[f][r]);
            }
            lp[f] += (p0[0] + p0[1]) + (p0[2] + p0[3]) + (p1[0] + p1[1]) + (p1[2] + p1[3]);
            union { u32x4 u; short8 s; } cv;
            cv.u[0] = pk2(p0[0], p0[1]);
            cv.u[1] = pk2(p0[2], p0[3]);
            cv.u[2] = pk2(p1[0], p1[1]);
            cv.u[3] = pk2(p1[2], p1[3]);
            accA[f] = mfma16(va0, cv.s, accA[f]);
            accB[f] = mfma16(va1, cv.s, accB[f]);
        }
        kc0 = kn0; kc1 = kn1;
        #pragma unroll
        for (int f = 0; f < 4; f++) { bc0[f] = bn0[f]; bc1[f] = bn1[f]; }
    }

    // per-lane lp covers keys lquad*8..+7 of this slice; reduce across quads
    #pragma unroll
    for (int f = 0; f < 4; f++) {
        lp[f] += __shfl_xor(lp[f], 16);
        lp[f] += __shfl_xor(lp[f], 32);
    }
    #pragma unroll
    for (int f = 0; f < 4; f++) {
        *(f32x4*)&cA[qt][ks][f][lane][0] = accA[f];
        *(f32x4*)&cB[qt][ks][f][lane][0] = accB[f];
    }
    if (lquad == 0) {
        #pragma unroll
        for (int f = 0; f < 4; f++) cl[qt][ks][f][lrow] = lp[f];
    }
    __syncthreads();
    // epilogue: 8 waves <-> 8 (qt, frag) units
    {
        const int oqt = wave >> 2, of = wave & 3;
        f32x4 sA = *(const f32x4*)&cA[oqt][0][of][lane][0];
        f32x4 sB = *(const f32x4*)&cB[oqt][0][of][lane][0];
        #pragma unroll
        for (int w = 1; w < 4; w++) {
            sA += *(const f32x4*)&cA[oqt][w][of][lane][0];
            sB += *(const f32x4*)&cB[oqt][w][of][lane][0];
        }
        const float lt = cl[oqt][0][of][lrow] + cl[oqt][1][of][lrow]
                       + cl[oqt][2][of][lrow] + cl[oqt][3][of][lrow];
        const float inv = 1.0f / lt;
        const int q = blockIdx.x * 128 + oqt * 64 + of * 16 + lrow;
        const size_t base = ((size_t)batch * NSEQ + q) * NINNER + head * DHEAD + lquad * 4;
        u16 h[8], l[8];
        #pragma unroll
        for (int r = 0; r < 4; r++) {
            split2(sA[r] * inv, h[r], l[r]);
            split2(sB[r] * inv, h[4 + r], l[4 + r]);
        }
        *(u32x2*)&o_hi[base] = *(u32x2*)&h[0];
        *(u32x2*)&o_hi[base + 16] = *(u32x2*)&h[4];
        *(u32x2*)&o_lo[base] = *(u32x2*)&l[0];
        *(u32x2*)&o_lo[base + 16] = *(u32x2*)&l[4];
    }
}

// ---------------- Kernel 4: output projection (64x64 tile) + bias ----------------
__global__ __launch_bounds__(256, 4) void out_kernel(
    const u16* __restrict__ o_hi, const u16* __restrict__ o_lo,
    const u16* __restrict__ wT_hi, const u16* __restrict__ wT_lo,
    const float* __restrict__ b_out,
    float* __restrict__ out)
{
    __shared__ __align__(16) u16 Ah[64][40], Al[64][40], Bh[64][40], Bl[64][40];
    const int t = threadIdx.x;
    const int wave = t >> 6, lane = t & 63;
    const int lrow = lane & 15, lquad = lane >> 4;
    const int rowBase = blockIdx.x * 64;
    const int colBase = blockIdx.y * 64;
    const int wm = (wave & 1) * 32;
    const int wn = (wave >> 1) * 32;
    const int kf = lquad * 8;
    const f32x4 zero = {0.f, 0.f, 0.f, 0.f};
    f32x4 acc[2][2];
    acc[0][0] = zero; acc[0][1] = zero; acc[1][0] = zero; acc[1][1] = zero;

    const int sr = t >> 2, sc = (t & 3) * 8;

    for (int k0 = 0; k0 < NINNER; k0 += 32) {
        __syncthreads();
        *(short8*)&Ah[sr][sc] = *(const short8*)(o_hi + (size_t)(rowBase + sr) * NINNER + k0 + sc);
        *(short8*)&Al[sr][sc] = *(const short8*)(o_lo + (size_t)(rowBase + sr) * NINNER + k0 + sc);
        *(short8*)&Bh[sr][sc] = *(const short8*)(wT_hi + (size_t)(colBase + sr) * NINNER + k0 + sc);
        *(short8*)&Bl[sr][sc] = *(const short8*)(wT_lo + (size_t)(colBase + sr) * NINNER + k0 + sc);
        __syncthreads();
        const short8 a0h = *(const short8*)&Ah[wm + lrow][kf];
        const short8 a0l = *(const short8*)&Al[wm + lrow][kf];
        const short8 a1h = *(const short8*)&Ah[wm + 16 + lrow][kf];
        const short8 a1l = *(const short8*)&Al[wm + 16 + lrow][kf];
        const short8 b0h = *(const short8*)&Bh[wn + lrow][kf];
        const short8 b0l = *(const short8*)&Bl[wn + lrow][kf];
        const short8 b1h = *(const short8*)&Bh[wn + 16 + lrow][kf];
        const short8 b1l = *(const short8*)&Bl[wn + 16 + lrow][kf];
        acc[0][0] = mfma16(a0h, b0h, acc[0][0]); acc[0][0] = mfma16(a0h, b0l, acc[0][0]); acc[0][0] = mfma16(a0l, b0h, acc[0][0]);
        acc[0][1] = mfma16(a0h, b1h, acc[0][1]); acc[0][1] = mfma16(a0h, b1l, acc[0][1]); acc[0][1] = mfma16(a0l, b1h, acc[0][1]);
        acc[1][0] = mfma16(a1h, b0h, acc[1][0]); acc[1][0] = mfma16(a1h, b0l, acc[1][0]); acc[1][0] = mfma16(a1l, b0h, acc[1][0]);
        acc[1][1] = mfma16(a1h, b1h, acc[1][1]); acc[1][1] = mfma16(a1h, b1l, acc[1][1]); acc[1][1] = mfma16(a1l, b1h, acc[1][1]);
    }

    #pragma unroll
    for (int mi = 0; mi < 2; mi++) {
        #pragma unroll
        for (int ni = 0; ni < 2; ni++) {
            #pragma unroll
            for (int r = 0; r < 4; r++) {
                const int grow = rowBase + wm + mi * 16 + lquad * 4 + r;
                const int gcol = colBase + wn + ni * 16 + lrow;
                out[(size_t)grow * NDIM + gcol] = acc[mi][ni][r] + b_out[gcol];
            }
        }
    }
}

extern "C" void kernel_launch(void* const* d_in, const int* in_sizes, int n_in,
                              void* d_out, int out_size, void* d_ws, size_t ws_size,
                              hipStream_t stream)
{
    (void)in_sizes; (void)n_in; (void)out_size; (void)ws_size;
    const float* x     = (const float*)d_in[0];
    const float* bias  = (const float*)d_in[1];
    const float* gamma = (const float*)d_in[2];
    const float* wqkv  = (const float*)d_in[3];
    const float* wout  = (const float*)d_in[4];
    const float* bout  = (const float*)d_in[5];
    float* out = (float*)d_out;

    char* ws = (char*)d_ws;
    size_t off = 0;
    auto carve = [&](size_t bytes) -> void* {
        void* p = (void*)(ws + off);
        off += (bytes + 255) & ~(size_t)255;
        return p;
    };
    const size_t rows = (size_t)NB * NSEQ;                 // 4096
    const size_t hn = (size_t)NB * NHEAD * NSEQ * DHEAD;   // 1,048,576
    u16* xn_hi = (u16*)carve(rows * NDIM * 2);
    u16* xn_lo = (u16*)carve(rows * NDIM * 2);
    u16* wqT_hi = (u16*)carve((size_t)NQKV * NDIM * 2);
    u16* wqT_lo = (u16*)carve((size_t)NQKV * NDIM * 2);
    u16* woT_hi = (u16*)carve((size_t)NDIM * NINNER * 2);
    u16* woT_lo = (u16*)carve((size_t)NDIM * NINNER * 2);
    u16* q_hi  = (u16*)carve(hn * 2);
    u16* q_lo  = (u16*)carve(hn * 2);
    u16* k_hi  = (u16*)carve(hn * 2);
    u16* vbuf  = (u16*)carve(hn * 2);
    u16* vt    = (u16*)carve(hn * 2);
    u16* o_hi  = (u16*)carve(rows * NINNER * 2);
    u16* o_lo  = (u16*)carve(rows * NINNER * 2);

    ln_kernel<<<dim3((unsigned)rows), 256, 0, stream>>>(x, gamma, (u32*)xn_hi, (u32*)xn_lo);
    wtrans_kernel<<<dim3(128), 256, 0, stream>>>(wqkv, wqT_hi, wqT_lo, wout, woT_hi, woT_lo);
    qkv_kernel<<<dim3(64, 12), 256, 0, stream>>>(xn_hi, xn_lo, wqT_hi, wqT_lo,
                                                 q_hi, q_lo, k_hi, vbuf);
    vtrans_kernel<<<dim3(NSEQ / 64, NB * NHEAD), 256, 0, stream>>>(vbuf, vt);
    attn_kernel<<<dim3(16, 16), 512, 0, stream>>>(q_hi, q_lo, k_hi,
                                                  vt, bias, o_hi, o_lo);
    out_kernel<<<dim3(64, 8), 256, 0, stream>>>(o_hi, o_lo, woT_hi, woT_lo, bout, out);
}